// Round 1
// 1531.041 us; speedup vs baseline: 1.7004x; 1.7004x over previous
//
#include <hip/hip_runtime.h>
#include <hip/hip_bf16.h>
#include <math.h>

// Model constants (fixed by the reference)
constexpr int L = 4, D = 512, H = 8, DH = 64, FF = 2048, V = 32000, B = 2, T = 1024, WD = 32, BAND = 128;
constexpr float SCALE = 0.125f;  // 1/sqrt(64)

typedef __hip_bfloat16 bf16;
typedef __attribute__((ext_vector_type(8))) short short8;   // 8 bf16 = 4 VGPRs (MFMA A/B frag)
typedef __attribute__((ext_vector_type(4))) float floatx4;  // MFMA C/D frag

#define MFMA16(a, b, c) __builtin_amdgcn_mfma_f32_16x16x32_bf16(a, b, c, 0, 0, 0)

// async global->LDS, 16B per lane; LDS dest = wave-uniform base + lane*16
__device__ inline void gl_lds16(const void* g, void* l) {
    __builtin_amdgcn_global_load_lds((const __attribute__((address_space(1))) unsigned int*)g,
                                     (__attribute__((address_space(3))) unsigned int*)l, 16, 0, 0);
}

// ---------------------------------------------------------------------------
// Embedding: x[b,t,:] = wte[idx[b,t],:] + wpe[t,:]
// ---------------------------------------------------------------------------
__global__ __launch_bounds__(256) void embed_k(const int* __restrict__ idx,
                                               const float* __restrict__ wte,
                                               const float* __restrict__ wpe,
                                               float* __restrict__ x) {
    int row = blockIdx.x;
    int t = row % T;
    int token = idx[row];
    const float* we = wte + (size_t)token * D;
    const float* pe = wpe + (size_t)t * D;
    float* xo = x + (size_t)row * D;
    for (int d = threadIdx.x; d < D; d += 256) xo[d] = we[d] + pe[d];
}

// ---------------------------------------------------------------------------
// fp32 -> bf16 convert (weights), 4 elems/thread
// ---------------------------------------------------------------------------
__global__ __launch_bounds__(256) void f2b_k(const float* __restrict__ in,
                                             bf16* __restrict__ out, int n4) {
    int i = blockIdx.x * 256 + threadIdx.x;
    if (i >= n4) return;
    float4 v = *(const float4*)&in[(size_t)i * 4];
    bf16 o[4] = {__float2bfloat16(v.x), __float2bfloat16(v.y),
                 __float2bfloat16(v.z), __float2bfloat16(v.w)};
    *(ulong1*)&out[(size_t)i * 4] = *(ulong1*)o;
}

// ---------------------------------------------------------------------------
// LayerNorm over D=512, one block (256 thr) per row -> bf16 output
// ---------------------------------------------------------------------------
__global__ __launch_bounds__(256) void ln_bf16_k(const float* __restrict__ x,
                                                 const float* __restrict__ g,
                                                 const float* __restrict__ b,
                                                 bf16* __restrict__ o) {
    int row = blockIdx.x;
    const float* xr = x + (size_t)row * D;
    int d0 = threadIdx.x, d1 = threadIdx.x + 256;
    float v0 = xr[d0], v1 = xr[d1];
    float s = v0 + v1, ss = v0 * v0 + v1 * v1;
    for (int off = 32; off > 0; off >>= 1) {
        s  += __shfl_down(s, off);
        ss += __shfl_down(ss, off);
    }
    __shared__ float red[2][4];
    int wid = threadIdx.x >> 6;
    if ((threadIdx.x & 63) == 0) { red[0][wid] = s; red[1][wid] = ss; }
    __syncthreads();
    s  = red[0][0] + red[0][1] + red[0][2] + red[0][3];
    ss = red[1][0] + red[1][1] + red[1][2] + red[1][3];
    float mean = s * (1.0f / D);
    float var  = ss * (1.0f / D) - mean * mean;
    float rstd = rsqrtf(var + 1e-5f);
    bf16* orow = o + (size_t)row * D;
    orow[d0] = __float2bfloat16((v0 - mean) * rstd * g[d0] + b[d0]);
    orow[d1] = __float2bfloat16((v1 - mean) * rstd * g[d1] + b[d1]);
}

// ---------------------------------------------------------------------------
// bf16 MFMA GEMM: C[m,n] = sum_k A[m,k]*W[n,k] (+bias)(+res), fp32 out.
// 128x128 tile, BK=32, 256 thr = 4 waves (2x2 of 64x64), 16x16x32 MFMA.
// EPI: 0=+bias, 1=+bias+res, 2=plain, 3=+bias -> bf16 out.
// ---------------------------------------------------------------------------
template <int EPI>
__global__ __launch_bounds__(256) void mgemm_k(const bf16* __restrict__ A,
                                               const bf16* __restrict__ W,
                                               const float* __restrict__ bias,
                                               const float* res,
                                               float* C, int M, int N, int K) {
    __shared__ __align__(16) bf16 As[128 * 32];
    __shared__ __align__(16) bf16 Bs[128 * 32];
    int tid = threadIdx.x;
    int wave = tid >> 6, lane = tid & 63;
    int quad = lane >> 4, l16 = lane & 15;
    int m0 = blockIdx.y * 128, n0 = blockIdx.x * 128;
    int wm = wave >> 1, wn = wave & 1;
    floatx4 acc[4][4] = {};

    int idx0 = tid, idx1 = tid + 256;
    const bf16* Ag0 = A + (size_t)(m0 + (idx0 >> 2)) * K + (idx0 & 3) * 8;
    const bf16* Ag1 = A + (size_t)(m0 + (idx1 >> 2)) * K + (idx1 & 3) * 8;
    const bf16* Wg0 = W + (size_t)(n0 + (idx0 >> 2)) * K + (idx0 & 3) * 8;
    const bf16* Wg1 = W + (size_t)(n0 + (idx1 >> 2)) * K + (idx1 & 3) * 8;
    bf16* lA0 = As + (size_t)(wave * 64) * 8;
    bf16* lA1 = As + (size_t)(256 + wave * 64) * 8;
    bf16* lB0 = Bs + (size_t)(wave * 64) * 8;
    bf16* lB1 = Bs + (size_t)(256 + wave * 64) * 8;

    for (int k0 = 0; k0 < K; k0 += 32) {
        __syncthreads();
        gl_lds16(Ag0 + k0, lA0);
        gl_lds16(Ag1 + k0, lA1);
        gl_lds16(Wg0 + k0, lB0);
        gl_lds16(Wg1 + k0, lB1);
        __syncthreads();
        short8 a[4], b[4];
#pragma unroll
        for (int mi = 0; mi < 4; mi++)
            a[mi] = *(const short8*)&As[(wm * 64 + mi * 16 + l16) * 32 + quad * 8];
#pragma unroll
        for (int ni = 0; ni < 4; ni++)
            b[ni] = *(const short8*)&Bs[(wn * 64 + ni * 16 + l16) * 32 + quad * 8];
#pragma unroll
        for (int mi = 0; mi < 4; mi++)
#pragma unroll
            for (int ni = 0; ni < 4; ni++)
                acc[mi][ni] = MFMA16(a[mi], b[ni], acc[mi][ni]);
    }

    int row_base = m0 + wm * 64 + quad * 4;
    int col_base = n0 + wn * 64 + l16;
#pragma unroll
    for (int mi = 0; mi < 4; mi++) {
#pragma unroll
        for (int r = 0; r < 4; r++) {
            int m = row_base + mi * 16 + r;
#pragma unroll
            for (int ni = 0; ni < 4; ni++) {
                int n = col_base + ni * 16;
                float v = acc[mi][ni][r];
                if (EPI == 0 || EPI == 1 || EPI == 3) v += bias[n];
                if (EPI == 1) v += res[(size_t)m * N + n];
                if (EPI == 3) {
                    ((bf16*)C)[(size_t)m * N + n] = __float2bfloat16(v);
                } else {
                    C[(size_t)m * N + n] = v;
                }
            }
        }
    }
}

// ---------------------------------------------------------------------------
// SWIGLU elementwise: out = silu(g)*v -> bf16, 4 elems/thread
// ---------------------------------------------------------------------------
__global__ __launch_bounds__(256) void swiglu_k(const float* __restrict__ g,
                                                const float* __restrict__ v,
                                                bf16* __restrict__ out, int n4) {
    int i = blockIdx.x * 256 + threadIdx.x;
    if (i >= n4) return;
    float4 gv = *(const float4*)&g[(size_t)i * 4];
    float4 vv = *(const float4*)&v[(size_t)i * 4];
    float r0 = gv.x / (1.0f + __expf(-gv.x)) * vv.x;
    float r1 = gv.y / (1.0f + __expf(-gv.y)) * vv.y;
    float r2 = gv.z / (1.0f + __expf(-gv.z)) * vv.z;
    float r3 = gv.w / (1.0f + __expf(-gv.w)) * vv.w;
    bf16 o[4] = {__float2bfloat16(r0), __float2bfloat16(r1),
                 __float2bfloat16(r2), __float2bfloat16(r3)};
    *(ulong1*)&out[(size_t)i * 4] = *(ulong1*)o;
}

// ---------------------------------------------------------------------------
// V transpose: vT[b,h,d,t] = qkvb[b,t,2D+h*64+d]  (bf16, 2 MB total)
// ---------------------------------------------------------------------------
__global__ __launch_bounds__(256) void vt_k(const bf16* __restrict__ qkvb,
                                            bf16* __restrict__ vT) {
    int bh = blockIdx.y, b = bh >> 3, h = bh & 7;
    int t0 = blockIdx.x * 64;
    __shared__ bf16 Ls[64][72];  // +8 pad
    int tid = threadIdx.x;
#pragma unroll
    for (int it = 0; it < 2; it++) {
        int c = it * 256 + tid;
        int r = c >> 3, s = c & 7;
        *(short8*)&Ls[r][s * 8] =
            *(const short8*)&qkvb[((size_t)(b * T + t0 + r)) * (3 * D) + 2 * D + h * DH + s * 8];
    }
    __syncthreads();
    int d = tid & 63;
    int tg = tid >> 6;
    for (int k = tg; k < 8; k += 4) {
        union { unsigned short u[8]; short8 v; } tmp;
#pragma unroll
        for (int e = 0; e < 8; e++) tmp.u[e] = *(const unsigned short*)&Ls[k * 8 + e][d];
        *(short8*)&vT[((size_t)bh * DH + d) * T + t0 + k * 8] = tmp.v;
    }
}

// ---------------------------------------------------------------------------
// QK^T via MFMA (bf16 in, fp32 raw scores out). 64x64 tile per block, 4 waves
// (2x2 of 32x32), K=DH=64. Causal tiles only (j0 <= i0+63). Scores *SCALE.
// LDS tiles are 64 bf16 (128 B) rows -> XOR-swizzle 16B chunks with (row&7):
// pre-swizzled global source + swizzled read (G4 / rule 21).
// ---------------------------------------------------------------------------
__global__ __launch_bounds__(256) void qk_mfma_k(const bf16* __restrict__ qkvb,
                                                 float* __restrict__ att) {
    int bh = blockIdx.z; int b = bh >> 3, h = bh & 7;
    int i0 = blockIdx.y * 64, j0 = blockIdx.x * 64;
    if (j0 > i0 + 63) return;
    __shared__ __align__(16) bf16 Qs[64 * 64];
    __shared__ __align__(16) bf16 Ks[64 * 64];
    int tid = threadIdx.x;
    int wave = tid >> 6, lane = tid & 63;
    int l16 = lane & 15, quad = lane >> 4;
    int wi = wave >> 1, wj = wave & 1;

    const bf16* Qbase = qkvb + ((size_t)(b * T + i0)) * (3 * D) + h * DH;
    const bf16* Kbase = qkvb + ((size_t)(b * T + j0)) * (3 * D) + D + h * DH;
#pragma unroll
    for (int it = 0; it < 2; it++) {
        int cbase = it * 256 + wave * 64;
        int c = cbase + lane;
        int r = c >> 3, s = c & 7, gs = s ^ (r & 7);
        gl_lds16(Qbase + (size_t)r * (3 * D) + gs * 8, Qs + (size_t)cbase * 8);
        gl_lds16(Kbase + (size_t)r * (3 * D) + gs * 8, Ks + (size_t)cbase * 8);
    }
    __syncthreads();

    floatx4 acc[2][2] = {};
#pragma unroll
    for (int ks = 0; ks < 2; ks++) {
        short8 a[2], bb[2];
#pragma unroll
        for (int mi = 0; mi < 2; mi++) {
            int row = wi * 32 + mi * 16 + l16;
            a[mi] = *(const short8*)&Qs[row * 64 + (((ks * 4 + quad) ^ (row & 7)) * 8)];
        }
#pragma unroll
        for (int ni = 0; ni < 2; ni++) {
            int row = wj * 32 + ni * 16 + l16;
            bb[ni] = *(const short8*)&Ks[row * 64 + (((ks * 4 + quad) ^ (row & 7)) * 8)];
        }
#pragma unroll
        for (int mi = 0; mi < 2; mi++)
#pragma unroll
            for (int ni = 0; ni < 2; ni++)
                acc[mi][ni] = MFMA16(a[mi], bb[ni], acc[mi][ni]);
    }

    size_t obase = ((size_t)bh * T + (i0 + wi * 32)) * T + (j0 + wj * 32);
#pragma unroll
    for (int mi = 0; mi < 2; mi++)
#pragma unroll
        for (int r = 0; r < 4; r++)
#pragma unroll
            for (int ni = 0; ni < 2; ni++)
                att[obase + (size_t)(mi * 16 + quad * 4 + r) * T + ni * 16 + l16] =
                    acc[mi][ni][r] * SCALE;
}

// ---------------------------------------------------------------------------
// Fused DAPE + ALiBi + mask + softmax. One block per (b,i) row (i reversed for
// load balance). Scores for 4 j's x 8 heads live in registers; DAPE MLP runs
// w-outer/c-inner; per-head block reduce; writes bf16 probs P + the static
// zero-pad regions the AV tiles read (j in (i, ia+63]; odd heads [js, i-128]).
// ---------------------------------------------------------------------------
__global__ __launch_bounds__(256) void dape_sm_k(const float* __restrict__ att,
                                                 bf16* __restrict__ P,
                                                 const float* __restrict__ gw,
                                                 const float* __restrict__ gb,
                                                 const float* __restrict__ vw,
                                                 const float* __restrict__ vb,
                                                 const float* __restrict__ ow,
                                                 const float* __restrict__ ob) {
    int bi = blockIdx.x;
    int b = bi >> 10;                 // T = 1024
    int i = (T - 1) - (bi & (T - 1)); // long rows first
    int tid = threadIdx.x;
    int wave = tid >> 6, lane = tid & 63;

    __shared__ float4 sgw[WD][2], svw[WD][2], sow[WD][2];
    __shared__ float sgb[WD], svb[WD], sob[H];
    __shared__ float redm[4][8], reds[4][8];
    if (tid < WD) {
        sgw[tid][0] = *(const float4*)&gw[tid * 2 * H];
        sgw[tid][1] = *(const float4*)&gw[tid * 2 * H + 4];
        svw[tid][0] = *(const float4*)&vw[tid * 2 * H];
        svw[tid][1] = *(const float4*)&vw[tid * 2 * H + 4];
        sgb[tid] = gb[tid]; svb[tid] = vb[tid];
        float o0[4], o1[4];
#pragma unroll
        for (int hh = 0; hh < 4; hh++) o0[hh] = ow[hh * WD + tid];
#pragma unroll
        for (int hh = 0; hh < 4; hh++) o1[hh] = ow[(hh + 4) * WD + tid];
        sow[tid][0] = *(float4*)o0;
        sow[tid][1] = *(float4*)o1;
    }
    if (tid < H) sob[tid] = ob[tid];
    __syncthreads();

    const float slopes[8] = {0.5f, 0.25f, 0.125f, 0.0625f,
                             0.03125f, 0.015625f, 0.0078125f, 0.00390625f};
    size_t abase = (size_t)b * H * T * T + (size_t)i * T;

    float sv[4][8];
    int jv[4];
#pragma unroll
    for (int c = 0; c < 4; c++) {
        int j = tid + c * 256;
        jv[c] = j;
        if (j <= i) {
#pragma unroll
            for (int hh = 0; hh < 8; hh++)
                sv[c][hh] = att[abase + (size_t)hh * T * T + j];
        }
    }

    // DAPE MLP: lb[c][h], weights loaded once per w, applied to all c
    float lb[4][8];
#pragma unroll
    for (int c = 0; c < 4; c++)
#pragma unroll
        for (int hh = 0; hh < 8; hh++) lb[c][hh] = sob[hh];
    for (int w = 0; w < WD; w++) {
        float4 g0 = sgw[w][0], g1 = sgw[w][1];
        float4 v0 = svw[w][0], v1 = svw[w][1];
        float4 o0 = sow[w][0], o1 = sow[w][1];
        float gbb = sgb[w], vbb = svb[w];
#pragma unroll
        for (int c = 0; c < 4; c++) {
            if (jv[c] <= i) {
                float g = gbb + sv[c][0] * g0.x + sv[c][1] * g0.y + sv[c][2] * g0.z + sv[c][3] * g0.w
                              + sv[c][4] * g1.x + sv[c][5] * g1.y + sv[c][6] * g1.z + sv[c][7] * g1.w;
                float v = vbb + sv[c][0] * v0.x + sv[c][1] * v0.y + sv[c][2] * v0.z + sv[c][3] * v0.w
                              + sv[c][4] * v1.x + sv[c][5] * v1.y + sv[c][6] * v1.z + sv[c][7] * v1.w;
                float hid = g / (1.0f + __expf(-g)) * v;
                lb[c][0] += hid * o0.x; lb[c][1] += hid * o0.y;
                lb[c][2] += hid * o0.z; lb[c][3] += hid * o0.w;
                lb[c][4] += hid * o1.x; lb[c][5] += hid * o1.y;
                lb[c][6] += hid * o1.z; lb[c][7] += hid * o1.w;
            }
        }
    }

    // score = s + lb + alibi; mask odd heads outside band
    float mx[8];
#pragma unroll
    for (int hh = 0; hh < 8; hh++) mx[hh] = -1e30f;
#pragma unroll
    for (int c = 0; c < 4; c++) {
        if (jv[c] <= i) {
            float diff = (float)(i - jv[c]);
#pragma unroll
            for (int hh = 0; hh < 8; hh++) {
                float val = sv[c][hh] + lb[c][hh] - slopes[hh] * diff;
                if ((hh & 1) && (jv[c] < i - (BAND - 1))) val = -1e30f;
                sv[c][hh] = val;
                mx[hh] = fmaxf(mx[hh], val);
            }
        }
    }
    // block max per head
    for (int off = 32; off > 0; off >>= 1)
#pragma unroll
        for (int hh = 0; hh < 8; hh++) mx[hh] = fmaxf(mx[hh], __shfl_down(mx[hh], off));
    if (lane == 0)
#pragma unroll
        for (int hh = 0; hh < 8; hh++) redm[wave][hh] = mx[hh];
    __syncthreads();
#pragma unroll
    for (int hh = 0; hh < 8; hh++)
        mx[hh] = fmaxf(fmaxf(redm[0][hh], redm[1][hh]), fmaxf(redm[2][hh], redm[3][hh]));

    // exp + sum
    float sm[8];
#pragma unroll
    for (int hh = 0; hh < 8; hh++) sm[hh] = 0.f;
#pragma unroll
    for (int c = 0; c < 4; c++) {
        if (jv[c] <= i) {
#pragma unroll
            for (int hh = 0; hh < 8; hh++) {
                float p = __expf(sv[c][hh] - mx[hh]);  // masked -1e30 -> 0
                sv[c][hh] = p;
                sm[hh] += p;
            }
        }
    }
    for (int off = 32; off > 0; off >>= 1)
#pragma unroll
        for (int hh = 0; hh < 8; hh++) sm[hh] += __shfl_down(sm[hh], off);
    if (lane == 0)
#pragma unroll
        for (int hh = 0; hh < 8; hh++) reds[wave][hh] = sm[hh];
    __syncthreads();
    float inv[8];
#pragma unroll
    for (int hh = 0; hh < 8; hh++)
        inv[hh] = 1.0f / (reds[0][hh] + reds[1][hh] + reds[2][hh] + reds[3][hh]);

    // write probs
    size_t pbase = (size_t)b * H * T * T + (size_t)i * T;
#pragma unroll
    for (int c = 0; c < 4; c++) {
        if (jv[c] <= i) {
#pragma unroll
            for (int hh = 0; hh < 8; hh++)
                P[pbase + (size_t)hh * T * T + jv[c]] = __float2bfloat16(sv[c][hh] * inv[hh]);
        }
    }
    // zero-pad: j in (i, ia+63] for all heads; odd heads [js, i-BAND]
    int ia = i & ~63;
    int zhi = ia + 63;
    for (int j = i + 1 + tid; j <= zhi; j += 256)
#pragma unroll
        for (int hh = 0; hh < 8; hh++)
            P[pbase + (size_t)hh * T * T + j] = __float2bfloat16(0.f);
    int js = (ia - (BAND - 1) > 0 ? ia - (BAND - 1) : 0) & ~31;
    for (int j = js + tid; j <= i - BAND; j += 256)
#pragma unroll
        for (int hh = 1; hh < 8; hh += 2)
            P[pbase + (size_t)hh * T * T + j] = __float2bfloat16(0.f);
}

// ---------------------------------------------------------------------------
// AV via MFMA: y[b,i,h*64+d] = sum_j P[b,h,i,j] * vT[b,h,d,j]. 64x64 (i x d)
// tile per block, 4 waves (2x2 of 32x32), K-loop over 32-wide j-tiles
// (banded for odd heads). Rows are 32 bf16 (64 B) -> XOR-swizzle with (row>>1)&3.
// ---------------------------------------------------------------------------
__global__ __launch_bounds__(256) void av_mfma_k(const bf16* __restrict__ P,
                                                 const bf16* __restrict__ vT,
                                                 bf16* __restrict__ y) {
    int bh = blockIdx.y; int b = bh >> 3, h = bh & 7;
    int ia = blockIdx.x * 64;
    __shared__ __align__(16) bf16 Ps[64 * 32];
    __shared__ __align__(16) bf16 Vs[64 * 32];
    int tid = threadIdx.x, wave = tid >> 6, lane = tid & 63;
    int l16 = lane & 15, quad = lane >> 4;
    int wi = wave >> 1, wn = wave & 1;
    floatx4 acc[2][2] = {};

    int j_end = ia + 63;
    int j_start = (h & 1) ? ((ia - (BAND - 1) > 0 ? ia - (BAND - 1) : 0) & ~31) : 0;
    const bf16* Pbase = P + ((size_t)bh * T + ia) * T;
    const bf16* Vbase = vT + (size_t)bh * DH * T;
    int r = tid >> 2, s = tid & 3, gs = s ^ ((r >> 1) & 3);
    bf16* lP = Ps + (size_t)(wave * 64) * 8;
    bf16* lV = Vs + (size_t)(wave * 64) * 8;

    for (int j0 = j_start; j0 <= j_end; j0 += 32) {
        __syncthreads();
        gl_lds16(Pbase + (size_t)r * T + j0 + gs * 8, lP);
        gl_lds16(Vbase + (size_t)r * T + j0 + gs * 8, lV);
        __syncthreads();
        short8 a[2], bb[2];
#pragma unroll
        for (int mi = 0; mi < 2; mi++) {
            int row = wi * 32 + mi * 16 + l16;
            a[mi] = *(const short8*)&Ps[row * 32 + ((quad ^ ((row >> 1) & 3)) * 8)];
        }
#pragma unroll
        for (int ni = 0; ni < 2; ni++) {
            int row = wn * 32 + ni * 16 + l16;
            bb[ni] = *(const short8*)&Vs[row * 32 + ((quad ^ ((row >> 1) & 3)) * 8)];
        }
#pragma unroll
        for (int mi = 0; mi < 2; mi++)
#pragma unroll
            for (int ni = 0; ni < 2; ni++)
                acc[mi][ni] = MFMA16(a[mi], bb[ni], acc[mi][ni]);
    }

#pragma unroll
    for (int mi = 0; mi < 2; mi++)
#pragma unroll
        for (int rr = 0; rr < 4; rr++) {
            int i = ia + wi * 32 + mi * 16 + quad * 4 + rr;
#pragma unroll
            for (int ni = 0; ni < 2; ni++) {
                int d = wn * 32 + ni * 16 + l16;
                y[((size_t)(b * T + i)) * D + h * DH + d] = __float2bfloat16(acc[mi][ni][rr]);
            }
        }
}

// ---------------------------------------------------------------------------
extern "C" void kernel_launch(void* const* d_in, const int* in_sizes, int n_in,
                              void* d_out, int out_size, void* d_ws, size_t ws_size,
                              hipStream_t stream) {
    const int*   idx     = (const int*)d_in[0];
    const float* wte     = (const float*)d_in[1];
    const float* wpe     = (const float*)d_in[2];
    const float* ln1_g   = (const float*)d_in[3];
    const float* ln1_b   = (const float*)d_in[4];
    const float* attn_w  = (const float*)d_in[5];
    const float* attn_b  = (const float*)d_in[6];
    const float* proj_w  = (const float*)d_in[7];
    const float* proj_b  = (const float*)d_in[8];
    const float* dape_gw = (const float*)d_in[9];
    const float* dape_gb = (const float*)d_in[10];
    const float* dape_vw = (const float*)d_in[11];
    const float* dape_vb = (const float*)d_in[12];
    const float* dape_ow = (const float*)d_in[13];
    const float* dape_ob = (const float*)d_in[14];
    const float* ln2_g   = (const float*)d_in[15];
    const float* ln2_b   = (const float*)d_in[16];
    const float* gate_w  = (const float*)d_in[17];
    const float* gate_b  = (const float*)d_in[18];
    const float* val_w   = (const float*)d_in[19];
    const float* val_b   = (const float*)d_in[20];
    const float* mlp_w   = (const float*)d_in[21];
    const float* mlp_b   = (const float*)d_in[22];
    const float* lnf_g   = (const float*)d_in[23];
    const float* lnf_b   = (const float*)d_in[24];
    const float* lm_w    = (const float*)d_in[25];
    float* out = (float*)d_out;

    // Workspace: fp32 region then bf16 region (~193 MB total).
    float* ws   = (float*)d_ws;
    float* x    = ws;                            // B*T*D
    float* att  = x + (size_t)B * T * D;         // B*H*T*T (raw scores)
    float* gbuf = att;                           // alias, B*T*FF (att dead in MLP phase)
    float* vbuf = att + (size_t)B * T * FF;      // alias, B*T*FF
    bf16*  hb   = (bf16*)(att + (size_t)B * H * T * T);  // B*T*D
    bf16*  yb   = hb   + (size_t)B * T * D;              // B*T*D
    bf16*  ffb  = yb   + (size_t)B * T * D;              // B*T*FF
    bf16*  qkvb = ffb  + (size_t)B * T * FF;             // B*T*3D
    bf16*  vTb  = qkvb + (size_t)B * T * 3 * D;          // B*H*DH*T
    bf16*  Pb   = vTb  + (size_t)B * H * DH * T;         // B*H*T*T (probs)
    bf16*  wq   = Pb   + (size_t)B * H * T * T;          // L*3D*D
    bf16*  wp   = wq   + (size_t)L * 3 * D * D;          // L*D*D
    bf16*  wg   = wp   + (size_t)L * D * D;              // L*FF*D
    bf16*  wv   = wg   + (size_t)L * FF * D;             // L*FF*D
    bf16*  wm   = wv   + (size_t)L * FF * D;             // L*D*FF
    bf16*  wl   = wm   + (size_t)L * D * FF;             // V*D

    auto conv = [&](const float* src, bf16* dst, size_t n) {
        int n4 = (int)(n / 4);
        f2b_k<<<(n4 + 255) / 256, 256, 0, stream>>>(src, dst, n4);
    };
    conv(attn_w, wq, (size_t)L * 3 * D * D);
    conv(proj_w, wp, (size_t)L * D * D);
    conv(gate_w, wg, (size_t)L * FF * D);
    conv(val_w,  wv, (size_t)L * FF * D);
    conv(mlp_w,  wm, (size_t)L * D * FF);
    conv(lm_w,   wl, (size_t)V * D);

    embed_k<<<B * T, 256, 0, stream>>>(idx, wte, wpe, x);

    const int M = B * T;
    for (int l = 0; l < L; l++) {
        ln_bf16_k<<<M, 256, 0, stream>>>(x, ln1_g + l * D, ln1_b + l * D, hb);
        mgemm_k<3><<<dim3(3 * D / 128, M / 128), 256, 0, stream>>>(
            hb, wq + (size_t)l * 3 * D * D, attn_b + l * 3 * D, nullptr, (float*)qkvb, M, 3 * D, D);
        vt_k<<<dim3(T / 64, B * H), 256, 0, stream>>>(qkvb, vTb);
        qk_mfma_k<<<dim3(T / 64, T / 64, B * H), 256, 0, stream>>>(qkvb, att);
        dape_sm_k<<<B * T, 256, 0, stream>>>(att, Pb,
            dape_gw + l * WD * 2 * H, dape_gb + l * WD,
            dape_vw + l * WD * 2 * H, dape_vb + l * WD,
            dape_ow + l * H * WD, dape_ob + l * H);
        av_mfma_k<<<dim3(T / 64, B * H), 256, 0, stream>>>(Pb, vTb, yb);
        mgemm_k<1><<<dim3(D / 128, M / 128), 256, 0, stream>>>(
            yb, wp + (size_t)l * D * D, proj_b + l * D, x, x, M, D, D);
        ln_bf16_k<<<M, 256, 0, stream>>>(x, ln2_g + l * D, ln2_b + l * D, hb);
        mgemm_k<0><<<dim3(FF / 128, M / 128), 256, 0, stream>>>(
            hb, wg + (size_t)l * FF * D, gate_b + l * FF, nullptr, gbuf, M, FF, D);
        mgemm_k<0><<<dim3(FF / 128, M / 128), 256, 0, stream>>>(
            hb, wv + (size_t)l * FF * D, val_b + l * FF, nullptr, vbuf, M, FF, D);
        {
            int n4 = B * T * FF / 4;
            swiglu_k<<<(n4 + 255) / 256, 256, 0, stream>>>(gbuf, vbuf, ffb, n4);
        }
        mgemm_k<1><<<dim3(D / 128, M / 128), 256, 0, stream>>>(
            ffb, wm + (size_t)l * D * FF, mlp_b + l * D, x, x, M, D, FF);
    }

    ln_bf16_k<<<M, 256, 0, stream>>>(x, lnf_g, lnf_b, hb);
    mgemm_k<2><<<dim3(V / 128, M / 128), 256, 0, stream>>>(
        hb, wl, nullptr, nullptr, out, M, V, D);
}

// Round 2
// 1326.788 us; speedup vs baseline: 1.9622x; 1.1539x over previous
//
#include <hip/hip_runtime.h>
#include <hip/hip_bf16.h>
#include <math.h>

// Model constants (fixed by the reference)
constexpr int L = 4, D = 512, H = 8, DH = 64, FF = 2048, V = 32000, B = 2, T = 1024, WD = 32, BAND = 128;
constexpr float SCALE = 0.125f;  // 1/sqrt(64)

typedef __hip_bfloat16 bf16;
typedef __attribute__((ext_vector_type(8))) short short8;   // 8 bf16 = 4 VGPRs (MFMA A/B frag)
typedef __attribute__((ext_vector_type(4))) float floatx4;  // MFMA C/D frag

#define MFMA16(a, b, c) __builtin_amdgcn_mfma_f32_16x16x32_bf16(a, b, c, 0, 0, 0)

// async global->LDS, 16B per lane; LDS dest = wave-uniform base + lane*16
__device__ inline void gl_lds16(const void* g, void* l) {
    __builtin_amdgcn_global_load_lds((const __attribute__((address_space(1))) unsigned int*)g,
                                     (__attribute__((address_space(3))) unsigned int*)l, 16, 0, 0);
}

// ---------------------------------------------------------------------------
// Embedding: x[b,t,:] = wte[idx[b,t],:] + wpe[t,:]
// ---------------------------------------------------------------------------
__global__ __launch_bounds__(256) void embed_k(const int* __restrict__ idx,
                                               const float* __restrict__ wte,
                                               const float* __restrict__ wpe,
                                               float* __restrict__ x) {
    int row = blockIdx.x;
    int t = row % T;
    int token = idx[row];
    const float* we = wte + (size_t)token * D;
    const float* pe = wpe + (size_t)t * D;
    float* xo = x + (size_t)row * D;
    for (int d = threadIdx.x; d < D; d += 256) xo[d] = we[d] + pe[d];
}

// ---------------------------------------------------------------------------
// fp32 -> bf16 convert (weights), 4 elems/thread
// ---------------------------------------------------------------------------
__global__ __launch_bounds__(256) void f2b_k(const float* __restrict__ in,
                                             bf16* __restrict__ out, int n4) {
    int i = blockIdx.x * 256 + threadIdx.x;
    if (i >= n4) return;
    float4 v = *(const float4*)&in[(size_t)i * 4];
    bf16 o[4] = {__float2bfloat16(v.x), __float2bfloat16(v.y),
                 __float2bfloat16(v.z), __float2bfloat16(v.w)};
    *(ulong1*)&out[(size_t)i * 4] = *(ulong1*)o;
}

// ---------------------------------------------------------------------------
// LayerNorm over D=512, one block (256 thr) per row -> bf16 output
// ---------------------------------------------------------------------------
__global__ __launch_bounds__(256) void ln_bf16_k(const float* __restrict__ x,
                                                 const float* __restrict__ g,
                                                 const float* __restrict__ b,
                                                 bf16* __restrict__ o) {
    int row = blockIdx.x;
    const float* xr = x + (size_t)row * D;
    int d0 = threadIdx.x, d1 = threadIdx.x + 256;
    float v0 = xr[d0], v1 = xr[d1];
    float s = v0 + v1, ss = v0 * v0 + v1 * v1;
    for (int off = 32; off > 0; off >>= 1) {
        s  += __shfl_down(s, off);
        ss += __shfl_down(ss, off);
    }
    __shared__ float red[2][4];
    int wid = threadIdx.x >> 6;
    if ((threadIdx.x & 63) == 0) { red[0][wid] = s; red[1][wid] = ss; }
    __syncthreads();
    s  = red[0][0] + red[0][1] + red[0][2] + red[0][3];
    ss = red[1][0] + red[1][1] + red[1][2] + red[1][3];
    float mean = s * (1.0f / D);
    float var  = ss * (1.0f / D) - mean * mean;
    float rstd = rsqrtf(var + 1e-5f);
    bf16* orow = o + (size_t)row * D;
    orow[d0] = __float2bfloat16((v0 - mean) * rstd * g[d0] + b[d0]);
    orow[d1] = __float2bfloat16((v1 - mean) * rstd * g[d1] + b[d1]);
}

// ---------------------------------------------------------------------------
// bf16 MFMA GEMM: C[m,n] = sum_k A[m,k]*W[n,k] (+bias)(+res), fp32 out.
// Templated tile BM x BN (BM,BN in {64,128}), BK=32, 256 thr = 4 waves (2x2).
// EPI: 0=+bias, 1=+bias+res, 2=plain, 3=+bias -> bf16 out.
// ---------------------------------------------------------------------------
template <int BM, int BN, int EPI>
__global__ __launch_bounds__(256) void mgemm_k(const bf16* __restrict__ A,
                                               const bf16* __restrict__ W,
                                               const float* __restrict__ bias,
                                               const float* res,
                                               float* C, int M, int N, int K) {
    constexpr int WM = BM / 2, WN = BN / 2;    // per-wave tile
    constexpr int FM = WM / 16, FN = WN / 16;  // 16x16 frags per wave
    constexpr int CA = BM / 64, CB = BN / 64;  // 16B-chunk staging rounds
    __shared__ __align__(16) bf16 As[BM * 32];
    __shared__ __align__(16) bf16 Bs[BN * 32];
    int tid = threadIdx.x;
    int wave = tid >> 6, lane = tid & 63;
    int quad = lane >> 4, l16 = lane & 15;
    int m0 = blockIdx.y * BM, n0 = blockIdx.x * BN;
    int wm = wave >> 1, wn = wave & 1;
    floatx4 acc[FM][FN] = {};

    const bf16* Ag[CA];
    const bf16* Wg[CB];
    bf16* lA[CA];
    bf16* lB[CB];
#pragma unroll
    for (int c = 0; c < CA; c++) {
        int idx = c * 256 + tid;
        Ag[c] = A + (size_t)(m0 + (idx >> 2)) * K + (idx & 3) * 8;
        lA[c] = As + (size_t)(c * 256 + wave * 64) * 8;
    }
#pragma unroll
    for (int c = 0; c < CB; c++) {
        int idx = c * 256 + tid;
        Wg[c] = W + (size_t)(n0 + (idx >> 2)) * K + (idx & 3) * 8;
        lB[c] = Bs + (size_t)(c * 256 + wave * 64) * 8;
    }

    for (int k0 = 0; k0 < K; k0 += 32) {
        __syncthreads();
#pragma unroll
        for (int c = 0; c < CA; c++) gl_lds16(Ag[c] + k0, lA[c]);
#pragma unroll
        for (int c = 0; c < CB; c++) gl_lds16(Wg[c] + k0, lB[c]);
        __syncthreads();
        short8 a[FM], b[FN];
#pragma unroll
        for (int mi = 0; mi < FM; mi++)
            a[mi] = *(const short8*)&As[(wm * WM + mi * 16 + l16) * 32 + quad * 8];
#pragma unroll
        for (int ni = 0; ni < FN; ni++)
            b[ni] = *(const short8*)&Bs[(wn * WN + ni * 16 + l16) * 32 + quad * 8];
#pragma unroll
        for (int mi = 0; mi < FM; mi++)
#pragma unroll
            for (int ni = 0; ni < FN; ni++)
                acc[mi][ni] = MFMA16(a[mi], b[ni], acc[mi][ni]);
    }

    int row_base = m0 + wm * WM + quad * 4;
    int col_base = n0 + wn * WN + l16;
#pragma unroll
    for (int mi = 0; mi < FM; mi++) {
#pragma unroll
        for (int r = 0; r < 4; r++) {
            int m = row_base + mi * 16 + r;
#pragma unroll
            for (int ni = 0; ni < FN; ni++) {
                int n = col_base + ni * 16;
                float v = acc[mi][ni][r];
                if (EPI == 0 || EPI == 1 || EPI == 3) v += bias[n];
                if (EPI == 1) v += res[(size_t)m * N + n];
                if (EPI == 3) {
                    ((bf16*)C)[(size_t)m * N + n] = __float2bfloat16(v);
                } else {
                    C[(size_t)m * N + n] = v;
                }
            }
        }
    }
}

// ---------------------------------------------------------------------------
// Fused gate+val GEMM with SWIGLU epilogue: O[m,n] = silu(A.Wg^T + gb) *
// (A.Wv^T + vb) -> bf16. Tile 128x64, one A-read feeds both products.
// ---------------------------------------------------------------------------
__global__ __launch_bounds__(256) void mgemm_glu_k(const bf16* __restrict__ A,
                                                   const bf16* __restrict__ Wgp,
                                                   const bf16* __restrict__ Wvp,
                                                   const float* __restrict__ gbias,
                                                   const float* __restrict__ vbias,
                                                   bf16* __restrict__ O,
                                                   int M, int N, int K) {
    constexpr int BM = 128, BN = 64, WM = 64, WN = 32, FM = 4, FN = 2;
    __shared__ __align__(16) bf16 As[BM * 32];
    __shared__ __align__(16) bf16 Gs[BN * 32];
    __shared__ __align__(16) bf16 Vs[BN * 32];
    int tid = threadIdx.x;
    int wave = tid >> 6, lane = tid & 63;
    int quad = lane >> 4, l16 = lane & 15;
    int m0 = blockIdx.y * BM, n0 = blockIdx.x * BN;
    int wm = wave >> 1, wn = wave & 1;
    floatx4 accg[FM][FN] = {}, accv[FM][FN] = {};

    int idx0 = tid, idx1 = tid + 256;
    const bf16* Ag0 = A + (size_t)(m0 + (idx0 >> 2)) * K + (idx0 & 3) * 8;
    const bf16* Ag1 = A + (size_t)(m0 + (idx1 >> 2)) * K + (idx1 & 3) * 8;
    const bf16* Gg = Wgp + (size_t)(n0 + (idx0 >> 2)) * K + (idx0 & 3) * 8;
    const bf16* Vg = Wvp + (size_t)(n0 + (idx0 >> 2)) * K + (idx0 & 3) * 8;
    bf16* lA0 = As + (size_t)(wave * 64) * 8;
    bf16* lA1 = As + (size_t)(256 + wave * 64) * 8;
    bf16* lG = Gs + (size_t)(wave * 64) * 8;
    bf16* lV = Vs + (size_t)(wave * 64) * 8;

    for (int k0 = 0; k0 < K; k0 += 32) {
        __syncthreads();
        gl_lds16(Ag0 + k0, lA0);
        gl_lds16(Ag1 + k0, lA1);
        gl_lds16(Gg + k0, lG);
        gl_lds16(Vg + k0, lV);
        __syncthreads();
        short8 a[FM], g[FN], v[FN];
#pragma unroll
        for (int mi = 0; mi < FM; mi++)
            a[mi] = *(const short8*)&As[(wm * WM + mi * 16 + l16) * 32 + quad * 8];
#pragma unroll
        for (int ni = 0; ni < FN; ni++) {
            g[ni] = *(const short8*)&Gs[(wn * WN + ni * 16 + l16) * 32 + quad * 8];
            v[ni] = *(const short8*)&Vs[(wn * WN + ni * 16 + l16) * 32 + quad * 8];
        }
#pragma unroll
        for (int mi = 0; mi < FM; mi++)
#pragma unroll
            for (int ni = 0; ni < FN; ni++) {
                accg[mi][ni] = MFMA16(a[mi], g[ni], accg[mi][ni]);
                accv[mi][ni] = MFMA16(a[mi], v[ni], accv[mi][ni]);
            }
    }

    int row_base = m0 + wm * WM + quad * 4;
    int col_base = n0 + wn * WN + l16;
#pragma unroll
    for (int mi = 0; mi < FM; mi++) {
#pragma unroll
        for (int r = 0; r < 4; r++) {
            int m = row_base + mi * 16 + r;
#pragma unroll
            for (int ni = 0; ni < FN; ni++) {
                int n = col_base + ni * 16;
                float gv = accg[mi][ni][r] + gbias[n];
                float vv = accv[mi][ni][r] + vbias[n];
                float o = gv / (1.0f + __expf(-gv)) * vv;
                O[(size_t)m * N + n] = __float2bfloat16(o);
            }
        }
    }
}

// ---------------------------------------------------------------------------
// V transpose: vT[b,h,d,t] = qkvb[b,t,2D+h*64+d]  (bf16, 2 MB total)
// ---------------------------------------------------------------------------
__global__ __launch_bounds__(256) void vt_k(const bf16* __restrict__ qkvb,
                                            bf16* __restrict__ vT) {
    int bh = blockIdx.y, b = bh >> 3, h = bh & 7;
    int t0 = blockIdx.x * 64;
    __shared__ bf16 Ls[64][72];  // +8 pad
    int tid = threadIdx.x;
#pragma unroll
    for (int it = 0; it < 2; it++) {
        int c = it * 256 + tid;
        int r = c >> 3, s = c & 7;
        *(short8*)&Ls[r][s * 8] =
            *(const short8*)&qkvb[((size_t)(b * T + t0 + r)) * (3 * D) + 2 * D + h * DH + s * 8];
    }
    __syncthreads();
    int d = tid & 63;
    int tg = tid >> 6;
    for (int k = tg; k < 8; k += 4) {
        union { unsigned short u[8]; short8 v; } tmp;
#pragma unroll
        for (int e = 0; e < 8; e++) tmp.u[e] = *(const unsigned short*)&Ls[k * 8 + e][d];
        *(short8*)&vT[((size_t)bh * DH + d) * T + t0 + k * 8] = tmp.v;
    }
}

// ---------------------------------------------------------------------------
// QK^T via MFMA (bf16 in, fp32 raw scores out). 64x64 tile per block, 4 waves
// (2x2 of 32x32), K=DH=64. Causal tiles only (j0 <= i0+63). Scores *SCALE.
// LDS rows are 128 B -> XOR-swizzle 16B chunks with (row&7) (G4 / rule 21).
// ---------------------------------------------------------------------------
__global__ __launch_bounds__(256) void qk_mfma_k(const bf16* __restrict__ qkvb,
                                                 float* __restrict__ att) {
    int bh = blockIdx.z; int b = bh >> 3, h = bh & 7;
    int i0 = blockIdx.y * 64, j0 = blockIdx.x * 64;
    if (j0 > i0 + 63) return;
    __shared__ __align__(16) bf16 Qs[64 * 64];
    __shared__ __align__(16) bf16 Ks[64 * 64];
    int tid = threadIdx.x;
    int wave = tid >> 6, lane = tid & 63;
    int l16 = lane & 15, quad = lane >> 4;
    int wi = wave >> 1, wj = wave & 1;

    const bf16* Qbase = qkvb + ((size_t)(b * T + i0)) * (3 * D) + h * DH;
    const bf16* Kbase = qkvb + ((size_t)(b * T + j0)) * (3 * D) + D + h * DH;
#pragma unroll
    for (int it = 0; it < 2; it++) {
        int cbase = it * 256 + wave * 64;
        int c = cbase + lane;
        int r = c >> 3, s = c & 7, gs = s ^ (r & 7);
        gl_lds16(Qbase + (size_t)r * (3 * D) + gs * 8, Qs + (size_t)cbase * 8);
        gl_lds16(Kbase + (size_t)r * (3 * D) + gs * 8, Ks + (size_t)cbase * 8);
    }
    __syncthreads();

    floatx4 acc[2][2] = {};
#pragma unroll
    for (int ks = 0; ks < 2; ks++) {
        short8 a[2], bb[2];
#pragma unroll
        for (int mi = 0; mi < 2; mi++) {
            int row = wi * 32 + mi * 16 + l16;
            a[mi] = *(const short8*)&Qs[row * 64 + (((ks * 4 + quad) ^ (row & 7)) * 8)];
        }
#pragma unroll
        for (int ni = 0; ni < 2; ni++) {
            int row = wj * 32 + ni * 16 + l16;
            bb[ni] = *(const short8*)&Ks[row * 64 + (((ks * 4 + quad) ^ (row & 7)) * 8)];
        }
#pragma unroll
        for (int mi = 0; mi < 2; mi++)
#pragma unroll
            for (int ni = 0; ni < 2; ni++)
                acc[mi][ni] = MFMA16(a[mi], bb[ni], acc[mi][ni]);
    }

    size_t obase = ((size_t)bh * T + (i0 + wi * 32)) * T + (j0 + wj * 32);
#pragma unroll
    for (int mi = 0; mi < 2; mi++)
#pragma unroll
        for (int r = 0; r < 4; r++)
#pragma unroll
            for (int ni = 0; ni < 2; ni++)
                att[obase + (size_t)(mi * 16 + quad * 4 + r) * T + ni * 16 + l16] =
                    acc[mi][ni][r] * SCALE;
}

// ---------------------------------------------------------------------------
// Fused DAPE + ALiBi + mask + softmax. One block per (b,i) row (i reversed for
// load balance). Scores for 4 j's x 8 heads live in registers; DAPE MLP runs
// w-outer/c-inner; per-head block reduce; writes bf16 probs P + the static
// zero-pad regions the AV tiles read (j in (i, ia+63]; odd heads [js, i-128]).
// ---------------------------------------------------------------------------
__global__ __launch_bounds__(256) void dape_sm_k(const float* __restrict__ att,
                                                 bf16* __restrict__ P,
                                                 const float* __restrict__ gw,
                                                 const float* __restrict__ gb,
                                                 const float* __restrict__ vw,
                                                 const float* __restrict__ vb,
                                                 const float* __restrict__ ow,
                                                 const float* __restrict__ ob) {
    int bi = blockIdx.x;
    int b = bi >> 10;                 // T = 1024
    int i = (T - 1) - (bi & (T - 1)); // long rows first
    int tid = threadIdx.x;
    int wave = tid >> 6, lane = tid & 63;

    __shared__ float4 sgw[WD][2], svw[WD][2], sow[WD][2];
    __shared__ float sgb[WD], svb[WD], sob[H];
    __shared__ float redm[4][8], reds[4][8];
    if (tid < WD) {
        sgw[tid][0] = *(const float4*)&gw[tid * 2 * H];
        sgw[tid][1] = *(const float4*)&gw[tid * 2 * H + 4];
        svw[tid][0] = *(const float4*)&vw[tid * 2 * H];
        svw[tid][1] = *(const float4*)&vw[tid * 2 * H + 4];
        sgb[tid] = gb[tid]; svb[tid] = vb[tid];
        float o0[4], o1[4];
#pragma unroll
        for (int hh = 0; hh < 4; hh++) o0[hh] = ow[hh * WD + tid];
#pragma unroll
        for (int hh = 0; hh < 4; hh++) o1[hh] = ow[(hh + 4) * WD + tid];
        sow[tid][0] = *(float4*)o0;
        sow[tid][1] = *(float4*)o1;
    }
    if (tid < H) sob[tid] = ob[tid];
    __syncthreads();

    const float slopes[8] = {0.5f, 0.25f, 0.125f, 0.0625f,
                             0.03125f, 0.015625f, 0.0078125f, 0.00390625f};
    size_t abase = (size_t)b * H * T * T + (size_t)i * T;

    float sv[4][8];
    int jv[4];
#pragma unroll
    for (int c = 0; c < 4; c++) {
        int j = tid + c * 256;
        jv[c] = j;
        if (j <= i) {
#pragma unroll
            for (int hh = 0; hh < 8; hh++)
                sv[c][hh] = att[abase + (size_t)hh * T * T + j];
        }
    }

    // DAPE MLP: lb[c][h], weights loaded once per w, applied to all c
    float lb[4][8];
#pragma unroll
    for (int c = 0; c < 4; c++)
#pragma unroll
        for (int hh = 0; hh < 8; hh++) lb[c][hh] = sob[hh];
    for (int w = 0; w < WD; w++) {
        float4 g0 = sgw[w][0], g1 = sgw[w][1];
        float4 v0 = svw[w][0], v1 = svw[w][1];
        float4 o0 = sow[w][0], o1 = sow[w][1];
        float gbb = sgb[w], vbb = svb[w];
#pragma unroll
        for (int c = 0; c < 4; c++) {
            if (jv[c] <= i) {
                float g = gbb + sv[c][0] * g0.x + sv[c][1] * g0.y + sv[c][2] * g0.z + sv[c][3] * g0.w
                              + sv[c][4] * g1.x + sv[c][5] * g1.y + sv[c][6] * g1.z + sv[c][7] * g1.w;
                float v = vbb + sv[c][0] * v0.x + sv[c][1] * v0.y + sv[c][2] * v0.z + sv[c][3] * v0.w
                              + sv[c][4] * v1.x + sv[c][5] * v1.y + sv[c][6] * v1.z + sv[c][7] * v1.w;
                float hid = g / (1.0f + __expf(-g)) * v;
                lb[c][0] += hid * o0.x; lb[c][1] += hid * o0.y;
                lb[c][2] += hid * o0.z; lb[c][3] += hid * o0.w;
                lb[c][4] += hid * o1.x; lb[c][5] += hid * o1.y;
                lb[c][6] += hid * o1.z; lb[c][7] += hid * o1.w;
            }
        }
    }

    // score = s + lb + alibi; mask odd heads outside band
    float mx[8];
#pragma unroll
    for (int hh = 0; hh < 8; hh++) mx[hh] = -1e30f;
#pragma unroll
    for (int c = 0; c < 4; c++) {
        if (jv[c] <= i) {
            float diff = (float)(i - jv[c]);
#pragma unroll
            for (int hh = 0; hh < 8; hh++) {
                float val = sv[c][hh] + lb[c][hh] - slopes[hh] * diff;
                if ((hh & 1) && (jv[c] < i - (BAND - 1))) val = -1e30f;
                sv[c][hh] = val;
                mx[hh] = fmaxf(mx[hh], val);
            }
        }
    }
    // block max per head
    for (int off = 32; off > 0; off >>= 1)
#pragma unroll
        for (int hh = 0; hh < 8; hh++) mx[hh] = fmaxf(mx[hh], __shfl_down(mx[hh], off));
    if (lane == 0)
#pragma unroll
        for (int hh = 0; hh < 8; hh++) redm[wave][hh] = mx[hh];
    __syncthreads();
#pragma unroll
    for (int hh = 0; hh < 8; hh++)
        mx[hh] = fmaxf(fmaxf(redm[0][hh], redm[1][hh]), fmaxf(redm[2][hh], redm[3][hh]));

    // exp + sum
    float sm[8];
#pragma unroll
    for (int hh = 0; hh < 8; hh++) sm[hh] = 0.f;
#pragma unroll
    for (int c = 0; c < 4; c++) {
        if (jv[c] <= i) {
#pragma unroll
            for (int hh = 0; hh < 8; hh++) {
                float p = __expf(sv[c][hh] - mx[hh]);  // masked -1e30 -> 0
                sv[c][hh] = p;
                sm[hh] += p;
            }
        }
    }
    for (int off = 32; off > 0; off >>= 1)
#pragma unroll
        for (int hh = 0; hh < 8; hh++) sm[hh] += __shfl_down(sm[hh], off);
    if (lane == 0)
#pragma unroll
        for (int hh = 0; hh < 8; hh++) reds[wave][hh] = sm[hh];
    __syncthreads();
    float inv[8];
#pragma unroll
    for (int hh = 0; hh < 8; hh++)
        inv[hh] = 1.0f / (reds[0][hh] + reds[1][hh] + reds[2][hh] + reds[3][hh]);

    // write probs
    size_t pbase = (size_t)b * H * T * T + (size_t)i * T;
#pragma unroll
    for (int c = 0; c < 4; c++) {
        if (jv[c] <= i) {
#pragma unroll
            for (int hh = 0; hh < 8; hh++)
                P[pbase + (size_t)hh * T * T + jv[c]] = __float2bfloat16(sv[c][hh] * inv[hh]);
        }
    }
    // zero-pad: j in (i, ia+63] for all heads; odd heads [js, i-BAND]
    int ia = i & ~63;
    int zhi = ia + 63;
    for (int j = i + 1 + tid; j <= zhi; j += 256)
#pragma unroll
        for (int hh = 0; hh < 8; hh++)
            P[pbase + (size_t)hh * T * T + j] = __float2bfloat16(0.f);
    int js = (ia - (BAND - 1) > 0 ? ia - (BAND - 1) : 0) & ~31;
    for (int j = js + tid; j <= i - BAND; j += 256)
#pragma unroll
        for (int hh = 1; hh < 8; hh += 2)
            P[pbase + (size_t)hh * T * T + j] = __float2bfloat16(0.f);
}

// ---------------------------------------------------------------------------
// AV via MFMA: y[b,i,h*64+d] = sum_j P[b,h,i,j] * vT[b,h,d,j]. 64x64 (i x d)
// tile per block, 4 waves (2x2 of 32x32), K-loop over 32-wide j-tiles
// (banded for odd heads). Rows are 64 B -> XOR-swizzle with (row>>1)&3.
// ---------------------------------------------------------------------------
__global__ __launch_bounds__(256) void av_mfma_k(const bf16* __restrict__ P,
                                                 const bf16* __restrict__ vT,
                                                 bf16* __restrict__ y) {
    int bh = blockIdx.y; int b = bh >> 3, h = bh & 7;
    int ia = blockIdx.x * 64;
    __shared__ __align__(16) bf16 Ps[64 * 32];
    __shared__ __align__(16) bf16 Vs[64 * 32];
    int tid = threadIdx.x, wave = tid >> 6, lane = tid & 63;
    int l16 = lane & 15, quad = lane >> 4;
    int wi = wave >> 1, wn = wave & 1;
    floatx4 acc[2][2] = {};

    int j_end = ia + 63;
    int j_start = (h & 1) ? ((ia - (BAND - 1) > 0 ? ia - (BAND - 1) : 0) & ~31) : 0;
    const bf16* Pbase = P + ((size_t)bh * T + ia) * T;
    const bf16* Vbase = vT + (size_t)bh * DH * T;
    int r = tid >> 2, s = tid & 3, gs = s ^ ((r >> 1) & 3);
    bf16* lP = Ps + (size_t)(wave * 64) * 8;
    bf16* lV = Vs + (size_t)(wave * 64) * 8;

    for (int j0 = j_start; j0 <= j_end; j0 += 32) {
        __syncthreads();
        gl_lds16(Pbase + (size_t)r * T + j0 + gs * 8, lP);
        gl_lds16(Vbase + (size_t)r * T + j0 + gs * 8, lV);
        __syncthreads();
        short8 a[2], bb[2];
#pragma unroll
        for (int mi = 0; mi < 2; mi++) {
            int row = wi * 32 + mi * 16 + l16;
            a[mi] = *(const short8*)&Ps[row * 32 + ((quad ^ ((row >> 1) & 3)) * 8)];
        }
#pragma unroll
        for (int ni = 0; ni < 2; ni++) {
            int row = wn * 32 + ni * 16 + l16;
            bb[ni] = *(const short8*)&Vs[row * 32 + ((quad ^ ((row >> 1) & 3)) * 8)];
        }
#pragma unroll
        for (int mi = 0; mi < 2; mi++)
#pragma unroll
            for (int ni = 0; ni < 2; ni++)
                acc[mi][ni] = MFMA16(a[mi], bb[ni], acc[mi][ni]);
    }

#pragma unroll
    for (int mi = 0; mi < 2; mi++)
#pragma unroll
        for (int rr = 0; rr < 4; rr++) {
            int i = ia + wi * 32 + mi * 16 + quad * 4 + rr;
#pragma unroll
            for (int ni = 0; ni < 2; ni++) {
                int d = wn * 32 + ni * 16 + l16;
                y[((size_t)(b * T + i)) * D + h * DH + d] = __float2bfloat16(acc[mi][ni][rr]);
            }
        }
}

// ---------------------------------------------------------------------------
extern "C" void kernel_launch(void* const* d_in, const int* in_sizes, int n_in,
                              void* d_out, int out_size, void* d_ws, size_t ws_size,
                              hipStream_t stream) {
    const int*   idx     = (const int*)d_in[0];
    const float* wte     = (const float*)d_in[1];
    const float* wpe     = (const float*)d_in[2];
    const float* ln1_g   = (const float*)d_in[3];
    const float* ln1_b   = (const float*)d_in[4];
    const float* attn_w  = (const float*)d_in[5];
    const float* attn_b  = (const float*)d_in[6];
    const float* proj_w  = (const float*)d_in[7];
    const float* proj_b  = (const float*)d_in[8];
    const float* dape_gw = (const float*)d_in[9];
    const float* dape_gb = (const float*)d_in[10];
    const float* dape_vw = (const float*)d_in[11];
    const float* dape_vb = (const float*)d_in[12];
    const float* dape_ow = (const float*)d_in[13];
    const float* dape_ob = (const float*)d_in[14];
    const float* ln2_g   = (const float*)d_in[15];
    const float* ln2_b   = (const float*)d_in[16];
    const float* gate_w  = (const float*)d_in[17];
    const float* gate_b  = (const float*)d_in[18];
    const float* val_w   = (const float*)d_in[19];
    const float* val_b   = (const float*)d_in[20];
    const float* mlp_w   = (const float*)d_in[21];
    const float* mlp_b   = (const float*)d_in[22];
    const float* lnf_g   = (const float*)d_in[23];
    const float* lnf_b   = (const float*)d_in[24];
    const float* lm_w    = (const float*)d_in[25];
    float* out = (float*)d_out;

    // Workspace: fp32 region then bf16 region (~175 MB total).
    float* ws   = (float*)d_ws;
    float* x    = ws;                            // B*T*D
    float* att  = x + (size_t)B * T * D;         // B*H*T*T (raw scores)
    bf16*  hb   = (bf16*)(att + (size_t)B * H * T * T);  // B*T*D
    bf16*  yb   = hb   + (size_t)B * T * D;              // B*T*D
    bf16*  ffb  = yb   + (size_t)B * T * D;              // B*T*FF
    bf16*  qkvb = ffb  + (size_t)B * T * FF;             // B*T*3D
    bf16*  vTb  = qkvb + (size_t)B * T * 3 * D;          // B*H*DH*T
    bf16*  Pb   = vTb  + (size_t)B * H * DH * T;         // B*H*T*T (probs)
    bf16*  wq   = Pb   + (size_t)B * H * T * T;          // L*3D*D
    bf16*  wp   = wq   + (size_t)L * 3 * D * D;          // L*D*D
    bf16*  wg   = wp   + (size_t)L * D * D;              // L*FF*D
    bf16*  wv   = wg   + (size_t)L * FF * D;             // L*FF*D
    bf16*  wm   = wv   + (size_t)L * FF * D;             // L*D*FF
    bf16*  wl   = wm   + (size_t)L * D * FF;             // V*D

    auto conv = [&](const float* src, bf16* dst, size_t n) {
        int n4 = (int)(n / 4);
        f2b_k<<<(n4 + 255) / 256, 256, 0, stream>>>(src, dst, n4);
    };
    conv(attn_w, wq, (size_t)L * 3 * D * D);
    conv(proj_w, wp, (size_t)L * D * D);
    conv(gate_w, wg, (size_t)L * FF * D);
    conv(val_w,  wv, (size_t)L * FF * D);
    conv(mlp_w,  wm, (size_t)L * D * FF);
    conv(lm_w,   wl, (size_t)V * D);

    embed_k<<<B * T, 256, 0, stream>>>(idx, wte, wpe, x);

    const int M = B * T;
    for (int l = 0; l < L; l++) {
        ln_bf16_k<<<M, 256, 0, stream>>>(x, ln1_g + l * D, ln1_b + l * D, hb);
        mgemm_k<128, 64, 3><<<dim3(3 * D / 64, M / 128), 256, 0, stream>>>(
            hb, wq + (size_t)l * 3 * D * D, attn_b + l * 3 * D, nullptr, (float*)qkvb, M, 3 * D, D);
        vt_k<<<dim3(T / 64, B * H), 256, 0, stream>>>(qkvb, vTb);
        qk_mfma_k<<<dim3(T / 64, T / 64, B * H), 256, 0, stream>>>(qkvb, att);
        dape_sm_k<<<B * T, 256, 0, stream>>>(att, Pb,
            dape_gw + l * WD * 2 * H, dape_gb + l * WD,
            dape_vw + l * WD * 2 * H, dape_vb + l * WD,
            dape_ow + l * H * WD, dape_ob + l * H);
        av_mfma_k<<<dim3(T / 64, B * H), 256, 0, stream>>>(Pb, vTb, yb);
        mgemm_k<128, 64, 1><<<dim3(D / 64, M / 128), 256, 0, stream>>>(
            yb, wp + (size_t)l * D * D, proj_b + l * D, x, x, M, D, D);
        ln_bf16_k<<<M, 256, 0, stream>>>(x, ln2_g + l * D, ln2_b + l * D, hb);
        mgemm_glu_k<<<dim3(FF / 64, M / 128), 256, 0, stream>>>(
            hb, wg + (size_t)l * FF * D, wv + (size_t)l * FF * D,
            gate_b + l * FF, val_b + l * FF, ffb, M, FF, D);
        mgemm_k<128, 64, 1><<<dim3(D / 64, M / 128), 256, 0, stream>>>(
            ffb, wm + (size_t)l * D * FF, mlp_b + l * D, x, x, M, D, FF);
    }

    ln_bf16_k<<<M, 256, 0, stream>>>(x, lnf_g, lnf_b, hb);
    mgemm_k<128, 128, 2><<<dim3(V / 128, M / 128), 256, 0, stream>>>(
        hb, wl, nullptr, nullptr, out, M, V, D);
}

// Round 4
// 1283.365 us; speedup vs baseline: 2.0286x; 1.0338x over previous
//
#include <hip/hip_runtime.h>
#include <hip/hip_bf16.h>
#include <math.h>

// Model constants (fixed by the reference)
constexpr int L = 4, D = 512, H = 8, DH = 64, FF = 2048, V = 32000, B = 2, T = 1024, WD = 32, BAND = 128;
constexpr float SCALE = 0.125f;  // 1/sqrt(64)

typedef __hip_bfloat16 bf16;
typedef __attribute__((ext_vector_type(8))) short short8;   // 8 bf16 = 4 VGPRs (MFMA A/B frag)
typedef __attribute__((ext_vector_type(4))) float floatx4;  // MFMA C/D frag

#define MFMA16(a, b, c) __builtin_amdgcn_mfma_f32_16x16x32_bf16(a, b, c, 0, 0, 0)

// async global->LDS, 16B per lane; LDS dest = wave-uniform base + lane*16
__device__ inline void gl_lds16(const void* g, void* l) {
    __builtin_amdgcn_global_load_lds((const __attribute__((address_space(1))) unsigned int*)g,
                                     (__attribute__((address_space(3))) unsigned int*)l, 16, 0, 0);
}

// ---------------------------------------------------------------------------
// Embedding: x[b,t,:] = wte[idx[b,t],:] + wpe[t,:]
// ---------------------------------------------------------------------------
__global__ __launch_bounds__(256) void embed_k(const int* __restrict__ idx,
                                               const float* __restrict__ wte,
                                               const float* __restrict__ wpe,
                                               float* __restrict__ x) {
    int row = blockIdx.x;
    int t = row % T;
    int token = idx[row];
    const float* we = wte + (size_t)token * D;
    const float* pe = wpe + (size_t)t * D;
    float* xo = x + (size_t)row * D;
    for (int d = threadIdx.x; d < D; d += 256) xo[d] = we[d] + pe[d];
}

// ---------------------------------------------------------------------------
// fp32 -> bf16 convert (weights), 4 elems/thread
// ---------------------------------------------------------------------------
__global__ __launch_bounds__(256) void f2b_k(const float* __restrict__ in,
                                             bf16* __restrict__ out, int n4) {
    int i = blockIdx.x * 256 + threadIdx.x;
    if (i >= n4) return;
    float4 v = *(const float4*)&in[(size_t)i * 4];
    bf16 o[4] = {__float2bfloat16(v.x), __float2bfloat16(v.y),
                 __float2bfloat16(v.z), __float2bfloat16(v.w)};
    *(ulong1*)&out[(size_t)i * 4] = *(ulong1*)o;
}

// ---------------------------------------------------------------------------
// LayerNorm over D=512, one block (256 thr) per row -> bf16 output
// ---------------------------------------------------------------------------
__global__ __launch_bounds__(256) void ln_bf16_k(const float* __restrict__ x,
                                                 const float* __restrict__ g,
                                                 const float* __restrict__ b,
                                                 bf16* __restrict__ o) {
    int row = blockIdx.x;
    const float* xr = x + (size_t)row * D;
    int d0 = threadIdx.x, d1 = threadIdx.x + 256;
    float v0 = xr[d0], v1 = xr[d1];
    float s = v0 + v1, ss = v0 * v0 + v1 * v1;
    for (int off = 32; off > 0; off >>= 1) {
        s  += __shfl_down(s, off);
        ss += __shfl_down(ss, off);
    }
    __shared__ float red[2][4];
    int wid = threadIdx.x >> 6;
    if ((threadIdx.x & 63) == 0) { red[0][wid] = s; red[1][wid] = ss; }
    __syncthreads();
    s  = red[0][0] + red[0][1] + red[0][2] + red[0][3];
    ss = red[1][0] + red[1][1] + red[1][2] + red[1][3];
    float mean = s * (1.0f / D);
    float var  = ss * (1.0f / D) - mean * mean;
    float rstd = rsqrtf(var + 1e-5f);
    bf16* orow = o + (size_t)row * D;
    orow[d0] = __float2bfloat16((v0 - mean) * rstd * g[d0] + b[d0]);
    orow[d1] = __float2bfloat16((v1 - mean) * rstd * g[d1] + b[d1]);
}

// ---------------------------------------------------------------------------
// bf16 MFMA GEMM: C[m,n] = sum_k A[m,k]*W[n,k] (+bias)(+res), fp32 out.
// Tile BM x BN, BK in {32,64}, 256 thr = 4 waves (2x2). Double-buffered
// 2-phase: stage(next) issued BEFORE compute(cur); one __syncthreads per
// iter (its vmcnt(0) lands after compute -> load latency hidden).
// LDS rows XOR-swizzled (pre-swizzled global src + swizzled read, rule 21).
// EPI: 0=+bias, 1=+bias+res, 2=plain, 3=+bias -> bf16 out.
// ---------------------------------------------------------------------------
template <int BM, int BN, int BK, int EPI>
__global__ __launch_bounds__(256) void mgemm_k(const bf16* __restrict__ A,
                                               const bf16* __restrict__ W,
                                               const float* __restrict__ bias,
                                               const float* res,
                                               float* C, int M, int N, int K) {
    constexpr int WM = BM / 2, WN = BN / 2;    // per-wave tile
    constexpr int FM = WM / 16, FN = WN / 16;  // 16x16 frags per wave
    constexpr int RCH = BK / 8;                // 16B chunks per row
    constexpr int CA = BM * RCH / 256, CB = BN * RCH / 256;
    constexpr int KS = BK / 32;                // k-subtiles per BK
    __shared__ __align__(16) bf16 As[2][BM * BK];
    __shared__ __align__(16) bf16 Bs[2][BN * BK];
    int tid = threadIdx.x;
    int wave = tid >> 6, lane = tid & 63;
    int quad = lane >> 4, l16 = lane & 15;
    int m0 = blockIdx.y * BM, n0 = blockIdx.x * BN;
    int wm = wave >> 1, wn = wave & 1;
    floatx4 acc[FM][FN] = {};

    const bf16* Ag[CA];
    const bf16* Wg[CB];
#pragma unroll
    for (int c = 0; c < CA; c++) {
        int idx = c * 256 + tid, r = idx / RCH, s = idx % RCH;
        int gs = (RCH == 8) ? (s ^ (r & 7)) : (s ^ ((r >> 1) & 3));
        Ag[c] = A + (size_t)(m0 + r) * K + gs * 8;
    }
#pragma unroll
    for (int c = 0; c < CB; c++) {
        int idx = c * 256 + tid, r = idx / RCH, s = idx % RCH;
        int gs = (RCH == 8) ? (s ^ (r & 7)) : (s ^ ((r >> 1) & 3));
        Wg[c] = W + (size_t)(n0 + r) * K + gs * 8;
    }
    int ldsoff = wave * 64 * 8;  // bf16 offset of this wave's 1KB staging slot

    // prologue: stage tile 0 into buf 0
#pragma unroll
    for (int c = 0; c < CA; c++) gl_lds16(Ag[c], &As[0][c * 2048 + ldsoff]);
#pragma unroll
    for (int c = 0; c < CB; c++) gl_lds16(Wg[c], &Bs[0][c * 2048 + ldsoff]);
    __syncthreads();

    int p = 0;
    for (int k0 = 0; k0 < K; k0 += BK) {
        if (k0 + BK < K) {
#pragma unroll
            for (int c = 0; c < CA; c++) gl_lds16(Ag[c] + k0 + BK, &As[p ^ 1][c * 2048 + ldsoff]);
#pragma unroll
            for (int c = 0; c < CB; c++) gl_lds16(Wg[c] + k0 + BK, &Bs[p ^ 1][c * 2048 + ldsoff]);
        }
#pragma unroll
        for (int ksub = 0; ksub < KS; ksub++) {
            short8 a[FM], b[FN];
#pragma unroll
            for (int mi = 0; mi < FM; mi++) {
                int row = wm * WM + mi * 16 + l16;
                int cc = (ksub * 4 + quad) ^ ((RCH == 8) ? (row & 7) : ((row >> 1) & 3));
                a[mi] = *(const short8*)&As[p][row * BK + cc * 8];
            }
#pragma unroll
            for (int ni = 0; ni < FN; ni++) {
                int row = wn * WN + ni * 16 + l16;
                int cc = (ksub * 4 + quad) ^ ((RCH == 8) ? (row & 7) : ((row >> 1) & 3));
                b[ni] = *(const short8*)&Bs[p][row * BK + cc * 8];
            }
#pragma unroll
            for (int mi = 0; mi < FM; mi++)
#pragma unroll
                for (int ni = 0; ni < FN; ni++)
                    acc[mi][ni] = MFMA16(a[mi], b[ni], acc[mi][ni]);
        }
        __syncthreads();
        p ^= 1;
    }

    int row_base = m0 + wm * WM + quad * 4;
    int col_base = n0 + wn * WN + l16;
#pragma unroll
    for (int mi = 0; mi < FM; mi++) {
#pragma unroll
        for (int r = 0; r < 4; r++) {
            int m = row_base + mi * 16 + r;
#pragma unroll
            for (int ni = 0; ni < FN; ni++) {
                int n = col_base + ni * 16;
                float v = acc[mi][ni][r];
                if (EPI == 0 || EPI == 1 || EPI == 3) v += bias[n];
                if (EPI == 1) v += res[(size_t)m * N + n];
                if (EPI == 3) {
                    ((bf16*)C)[(size_t)m * N + n] = __float2bfloat16(v);
                } else {
                    C[(size_t)m * N + n] = v;
                }
            }
        }
    }
}

// ---------------------------------------------------------------------------
// Fused gate+val GEMM with SWIGLU epilogue: O[m,n] = silu(A.Wg^T + gb) *
// (A.Wv^T + vb) -> bf16. Tile 128x64, BK=32, double-buffered 2-phase,
// XOR-swizzled LDS (64B rows -> (row>>1)&3 on 16B chunks).
// ---------------------------------------------------------------------------
__global__ __launch_bounds__(256) void mgemm_glu_k(const bf16* __restrict__ A,
                                                   const bf16* __restrict__ Wgp,
                                                   const bf16* __restrict__ Wvp,
                                                   const float* __restrict__ gbias,
                                                   const float* __restrict__ vbias,
                                                   bf16* __restrict__ O,
                                                   int M, int N, int K) {
    constexpr int BM = 128, BN = 64, WM = 64, WN = 32, FM = 4, FN = 2;
    __shared__ __align__(16) bf16 As[2][BM * 32];
    __shared__ __align__(16) bf16 Gs[2][BN * 32];
    __shared__ __align__(16) bf16 Vs[2][BN * 32];
    int tid = threadIdx.x;
    int wave = tid >> 6, lane = tid & 63;
    int quad = lane >> 4, l16 = lane & 15;
    int m0 = blockIdx.y * BM, n0 = blockIdx.x * BN;
    int wm = wave >> 1, wn = wave & 1;
    floatx4 accg[FM][FN] = {}, accv[FM][FN] = {};

    const bf16* Ag[2];
#pragma unroll
    for (int c = 0; c < 2; c++) {
        int idx = c * 256 + tid, r = idx >> 2, s = idx & 3;
        int gs = s ^ ((r >> 1) & 3);
        Ag[c] = A + (size_t)(m0 + r) * K + gs * 8;
    }
    const bf16* Gg;
    const bf16* Vg;
    {
        int r = tid >> 2, s = tid & 3;
        int gs = s ^ ((r >> 1) & 3);
        Gg = Wgp + (size_t)(n0 + r) * K + gs * 8;
        Vg = Wvp + (size_t)(n0 + r) * K + gs * 8;
    }
    int ldsoff = wave * 64 * 8;

#pragma unroll
    for (int c = 0; c < 2; c++) gl_lds16(Ag[c], &As[0][c * 2048 + ldsoff]);
    gl_lds16(Gg, &Gs[0][ldsoff]);
    gl_lds16(Vg, &Vs[0][ldsoff]);
    __syncthreads();

    int p = 0;
    for (int k0 = 0; k0 < K; k0 += 32) {
        if (k0 + 32 < K) {
#pragma unroll
            for (int c = 0; c < 2; c++) gl_lds16(Ag[c] + k0 + 32, &As[p ^ 1][c * 2048 + ldsoff]);
            gl_lds16(Gg + k0 + 32, &Gs[p ^ 1][ldsoff]);
            gl_lds16(Vg + k0 + 32, &Vs[p ^ 1][ldsoff]);
        }
        short8 a[FM], g[FN], v[FN];
#pragma unroll
        for (int mi = 0; mi < FM; mi++) {
            int row = wm * WM + mi * 16 + l16;
            int cc = quad ^ ((row >> 1) & 3);
            a[mi] = *(const short8*)&As[p][row * 32 + cc * 8];
        }
#pragma unroll
        for (int ni = 0; ni < FN; ni++) {
            int row = wn * WN + ni * 16 + l16;
            int cc = quad ^ ((row >> 1) & 3);
            g[ni] = *(const short8*)&Gs[p][row * 32 + cc * 8];
            v[ni] = *(const short8*)&Vs[p][row * 32 + cc * 8];
        }
#pragma unroll
        for (int mi = 0; mi < FM; mi++)
#pragma unroll
            for (int ni = 0; ni < FN; ni++) {
                accg[mi][ni] = MFMA16(a[mi], g[ni], accg[mi][ni]);
                accv[mi][ni] = MFMA16(a[mi], v[ni], accv[mi][ni]);
            }
        __syncthreads();
        p ^= 1;
    }

    int row_base = m0 + wm * WM + quad * 4;
    int col_base = n0 + wn * WN + l16;
#pragma unroll
    for (int mi = 0; mi < FM; mi++) {
#pragma unroll
        for (int r = 0; r < 4; r++) {
            int m = row_base + mi * 16 + r;
#pragma unroll
            for (int ni = 0; ni < FN; ni++) {
                int n = col_base + ni * 16;
                float gv = accg[mi][ni][r] + gbias[n];
                float vv = accv[mi][ni][r] + vbias[n];
                float o = gv / (1.0f + __expf(-gv)) * vv;
                O[(size_t)m * N + n] = __float2bfloat16(o);
            }
        }
    }
}

// ---------------------------------------------------------------------------
// V transpose: vT[b,h,d,t] = qkvb[b,t,2D+h*64+d]  (bf16, 2 MB total)
// ---------------------------------------------------------------------------
__global__ __launch_bounds__(256) void vt_k(const bf16* __restrict__ qkvb,
                                            bf16* __restrict__ vT) {
    int bh = blockIdx.y, b = bh >> 3, h = bh & 7;
    int t0 = blockIdx.x * 64;
    __shared__ bf16 Ls[64][72];  // +8 pad
    int tid = threadIdx.x;
#pragma unroll
    for (int it = 0; it < 2; it++) {
        int c = it * 256 + tid;
        int r = c >> 3, s = c & 7;
        *(short8*)&Ls[r][s * 8] =
            *(const short8*)&qkvb[((size_t)(b * T + t0 + r)) * (3 * D) + 2 * D + h * DH + s * 8];
    }
    __syncthreads();
    int d = tid & 63;
    int tg = tid >> 6;
    for (int k = tg; k < 8; k += 4) {
        union { unsigned short u[8]; short8 v; } tmp;
#pragma unroll
        for (int e = 0; e < 8; e++) tmp.u[e] = *(const unsigned short*)&Ls[k * 8 + e][d];
        *(short8*)&vT[((size_t)bh * DH + d) * T + t0 + k * 8] = tmp.v;
    }
}

// ---------------------------------------------------------------------------
// QK^T via MFMA (bf16 in, fp32 raw scores out). 64x64 tile per block, 4 waves
// (2x2 of 32x32), K=DH=64. Causal tiles only (j0 <= i0+63). Scores *SCALE.
// LDS rows are 128 B -> XOR-swizzle 16B chunks with (row&7) (G4 / rule 21).
// ---------------------------------------------------------------------------
__global__ __launch_bounds__(256) void qk_mfma_k(const bf16* __restrict__ qkvb,
                                                 float* __restrict__ att) {
    int bh = blockIdx.z; int b = bh >> 3, h = bh & 7;
    int i0 = blockIdx.y * 64, j0 = blockIdx.x * 64;
    if (j0 > i0 + 63) return;
    __shared__ __align__(16) bf16 Qs[64 * 64];
    __shared__ __align__(16) bf16 Ks[64 * 64];
    int tid = threadIdx.x;
    int wave = tid >> 6, lane = tid & 63;
    int l16 = lane & 15, quad = lane >> 4;
    int wi = wave >> 1, wj = wave & 1;

    const bf16* Qbase = qkvb + ((size_t)(b * T + i0)) * (3 * D) + h * DH;
    const bf16* Kbase = qkvb + ((size_t)(b * T + j0)) * (3 * D) + D + h * DH;
#pragma unroll
    for (int it = 0; it < 2; it++) {
        int cbase = it * 256 + wave * 64;
        int c = cbase + lane;
        int r = c >> 3, s = c & 7, gs = s ^ (r & 7);
        gl_lds16(Qbase + (size_t)r * (3 * D) + gs * 8, Qs + (size_t)cbase * 8);
        gl_lds16(Kbase + (size_t)r * (3 * D) + gs * 8, Ks + (size_t)cbase * 8);
    }
    __syncthreads();

    floatx4 acc[2][2] = {};
#pragma unroll
    for (int ks = 0; ks < 2; ks++) {
        short8 a[2], bb[2];
#pragma unroll
        for (int mi = 0; mi < 2; mi++) {
            int row = wi * 32 + mi * 16 + l16;
            a[mi] = *(const short8*)&Qs[row * 64 + (((ks * 4 + quad) ^ (row & 7)) * 8)];
        }
#pragma unroll
        for (int ni = 0; ni < 2; ni++) {
            int row = wj * 32 + ni * 16 + l16;
            bb[ni] = *(const short8*)&Ks[row * 64 + (((ks * 4 + quad) ^ (row & 7)) * 8)];
        }
#pragma unroll
        for (int mi = 0; mi < 2; mi++)
#pragma unroll
            for (int ni = 0; ni < 2; ni++)
                acc[mi][ni] = MFMA16(a[mi], bb[ni], acc[mi][ni]);
    }

    size_t obase = ((size_t)bh * T + (i0 + wi * 32)) * T + (j0 + wj * 32);
#pragma unroll
    for (int mi = 0; mi < 2; mi++)
#pragma unroll
        for (int r = 0; r < 4; r++)
#pragma unroll
            for (int ni = 0; ni < 2; ni++)
                att[obase + (size_t)(mi * 16 + quad * 4 + r) * T + ni * 16 + l16] =
                    acc[mi][ni][r] * SCALE;
}

// ---------------------------------------------------------------------------
// Fused DAPE + ALiBi + mask + softmax. One block per (b,i) row (i reversed for
// load balance). Scores for 4 j's x 8 heads live in registers; DAPE MLP runs
// w-outer/c-inner; per-head block reduce; writes bf16 probs P + the static
// zero-pad regions the AV tiles read (j in (i, ia+63]; odd heads [js, i-128]).
// ---------------------------------------------------------------------------
__global__ __launch_bounds__(256) void dape_sm_k(const float* __restrict__ att,
                                                 bf16* __restrict__ P,
                                                 const float* __restrict__ gw,
                                                 const float* __restrict__ gb,
                                                 const float* __restrict__ vw,
                                                 const float* __restrict__ vb,
                                                 const float* __restrict__ ow,
                                                 const float* __restrict__ ob) {
    int bi = blockIdx.x;
    int b = bi >> 10;                 // T = 1024
    int i = (T - 1) - (bi & (T - 1)); // long rows first
    int tid = threadIdx.x;
    int wave = tid >> 6, lane = tid & 63;

    __shared__ float4 sgw[WD][2], svw[WD][2], sow[WD][2];
    __shared__ float sgb[WD], svb[WD], sob[H];
    __shared__ float redm[4][8], reds[4][8];
    if (tid < WD) {
        sgw[tid][0] = *(const float4*)&gw[tid * 2 * H];
        sgw[tid][1] = *(const float4*)&gw[tid * 2 * H + 4];
        svw[tid][0] = *(const float4*)&vw[tid * 2 * H];
        svw[tid][1] = *(const float4*)&vw[tid * 2 * H + 4];
        sgb[tid] = gb[tid]; svb[tid] = vb[tid];
        float o0[4], o1[4];
#pragma unroll
        for (int hh = 0; hh < 4; hh++) o0[hh] = ow[hh * WD + tid];
#pragma unroll
        for (int hh = 0; hh < 4; hh++) o1[hh] = ow[(hh + 4) * WD + tid];
        sow[tid][0] = *(float4*)o0;
        sow[tid][1] = *(float4*)o1;
    }
    if (tid < H) sob[tid] = ob[tid];
    __syncthreads();

    const float slopes[8] = {0.5f, 0.25f, 0.125f, 0.0625f,
                             0.03125f, 0.015625f, 0.0078125f, 0.00390625f};
    size_t abase = (size_t)b * H * T * T + (size_t)i * T;

    float sv[4][8];
    int jv[4];
#pragma unroll
    for (int c = 0; c < 4; c++) {
        int j = tid + c * 256;
        jv[c] = j;
        if (j <= i) {
#pragma unroll
            for (int hh = 0; hh < 8; hh++)
                sv[c][hh] = att[abase + (size_t)hh * T * T + j];
        }
    }

    // DAPE MLP: lb[c][h], weights loaded once per w, applied to all c
    float lb[4][8];
#pragma unroll
    for (int c = 0; c < 4; c++)
#pragma unroll
        for (int hh = 0; hh < 8; hh++) lb[c][hh] = sob[hh];
    for (int w = 0; w < WD; w++) {
        float4 g0 = sgw[w][0], g1 = sgw[w][1];
        float4 v0 = svw[w][0], v1 = svw[w][1];
        float4 o0 = sow[w][0], o1 = sow[w][1];
        float gbb = sgb[w], vbb = svb[w];
#pragma unroll
        for (int c = 0; c < 4; c++) {
            if (jv[c] <= i) {
                float g = gbb + sv[c][0] * g0.x + sv[c][1] * g0.y + sv[c][2] * g0.z + sv[c][3] * g0.w
                              + sv[c][4] * g1.x + sv[c][5] * g1.y + sv[c][6] * g1.z + sv[c][7] * g1.w;
                float v = vbb + sv[c][0] * v0.x + sv[c][1] * v0.y + sv[c][2] * v0.z + sv[c][3] * v0.w
                              + sv[c][4] * v1.x + sv[c][5] * v1.y + sv[c][6] * v1.z + sv[c][7] * v1.w;
                float hid = g / (1.0f + __expf(-g)) * v;
                lb[c][0] += hid * o0.x; lb[c][1] += hid * o0.y;
                lb[c][2] += hid * o0.z; lb[c][3] += hid * o0.w;
                lb[c][4] += hid * o1.x; lb[c][5] += hid * o1.y;
                lb[c][6] += hid * o1.z; lb[c][7] += hid * o1.w;
            }
        }
    }

    // score = s + lb + alibi; mask odd heads outside band
    float mx[8];
#pragma unroll
    for (int hh = 0; hh < 8; hh++) mx[hh] = -1e30f;
#pragma unroll
    for (int c = 0; c < 4; c++) {
        if (jv[c] <= i) {
            float diff = (float)(i - jv[c]);
#pragma unroll
            for (int hh = 0; hh < 8; hh++) {
                float val = sv[c][hh] + lb[c][hh] - slopes[hh] * diff;
                if ((hh & 1) && (jv[c] < i - (BAND - 1))) val = -1e30f;
                sv[c][hh] = val;
                mx[hh] = fmaxf(mx[hh], val);
            }
        }
    }
    // block max per head
    for (int off = 32; off > 0; off >>= 1)
#pragma unroll
        for (int hh = 0; hh < 8; hh++) mx[hh] = fmaxf(mx[hh], __shfl_down(mx[hh], off));
    if (lane == 0)
#pragma unroll
        for (int hh = 0; hh < 8; hh++) redm[wave][hh] = mx[hh];
    __syncthreads();
#pragma unroll
    for (int hh = 0; hh < 8; hh++)
        mx[hh] = fmaxf(fmaxf(redm[0][hh], redm[1][hh]), fmaxf(redm[2][hh], redm[3][hh]));

    // exp + sum
    float sm[8];
#pragma unroll
    for (int hh = 0; hh < 8; hh++) sm[hh] = 0.f;
#pragma unroll
    for (int c = 0; c < 4; c++) {
        if (jv[c] <= i) {
#pragma unroll
            for (int hh = 0; hh < 8; hh++) {
                float p = __expf(sv[c][hh] - mx[hh]);  // masked -1e30 -> 0
                sv[c][hh] = p;
                sm[hh] += p;
            }
        }
    }
    for (int off = 32; off > 0; off >>= 1)
#pragma unroll
        for (int hh = 0; hh < 8; hh++) sm[hh] += __shfl_down(sm[hh], off);
    if (lane == 0)
#pragma unroll
        for (int hh = 0; hh < 8; hh++) reds[wave][hh] = sm[hh];
    __syncthreads();
    float inv[8];
#pragma unroll
    for (int hh = 0; hh < 8; hh++)
        inv[hh] = 1.0f / (reds[0][hh] + reds[1][hh] + reds[2][hh] + reds[3][hh]);

    // write probs
    size_t pbase = (size_t)b * H * T * T + (size_t)i * T;
#pragma unroll
    for (int c = 0; c < 4; c++) {
        if (jv[c] <= i) {
#pragma unroll
            for (int hh = 0; hh < 8; hh++)
                P[pbase + (size_t)hh * T * T + jv[c]] = __float2bfloat16(sv[c][hh] * inv[hh]);
        }
    }
    // zero-pad: j in (i, ia+63] for all heads; odd heads [js, i-BAND]
    int ia = i & ~63;
    int zhi = ia + 63;
    for (int j = i + 1 + tid; j <= zhi; j += 256)
#pragma unroll
        for (int hh = 0; hh < 8; hh++)
            P[pbase + (size_t)hh * T * T + j] = __float2bfloat16(0.f);
    int js = (ia - (BAND - 1) > 0 ? ia - (BAND - 1) : 0) & ~31;
    for (int j = js + tid; j <= i - BAND; j += 256)
#pragma unroll
        for (int hh = 1; hh < 8; hh += 2)
            P[pbase + (size_t)hh * T * T + j] = __float2bfloat16(0.f);
}

// ---------------------------------------------------------------------------
// AV via MFMA: y[b,i,h*64+d] = sum_j P[b,h,i,j] * vT[b,h,d,j]. 64x64 (i x d)
// tile per block, 4 waves (2x2 of 32x32), K-loop over 32-wide j-tiles
// (banded for odd heads). Double-buffered 2-phase like mgemm.
// Rows are 64 B -> XOR-swizzle with (row>>1)&3.
// ---------------------------------------------------------------------------
__global__ __launch_bounds__(256) void av_mfma_k(const bf16* __restrict__ P,
                                                 const bf16* __restrict__ vT,
                                                 bf16* __restrict__ y) {
    int bh = blockIdx.y; int b = bh >> 3, h = bh & 7;
    int ia = blockIdx.x * 64;
    __shared__ __align__(16) bf16 Ps[2][64 * 32];
    __shared__ __align__(16) bf16 Vs[2][64 * 32];
    int tid = threadIdx.x, wave = tid >> 6, lane = tid & 63;
    int l16 = lane & 15, quad = lane >> 4;
    int wi = wave >> 1, wn = wave & 1;
    floatx4 acc[2][2] = {};

    int j_end = ia + 63;
    int j_start = (h & 1) ? ((ia - (BAND - 1) > 0 ? ia - (BAND - 1) : 0) & ~31) : 0;
    const bf16* Pbase = P + ((size_t)bh * T + ia) * T;
    const bf16* Vbase = vT + (size_t)bh * DH * T;
    int r = tid >> 2, s = tid & 3, gs = s ^ ((r >> 1) & 3);
    int ldsoff = wave * 64 * 8;

    gl_lds16(Pbase + (size_t)r * T + j_start + gs * 8, &Ps[0][ldsoff]);
    gl_lds16(Vbase + (size_t)r * T + j_start + gs * 8, &Vs[0][ldsoff]);
    __syncthreads();

    int p = 0;
    for (int j0 = j_start; j0 <= j_end; j0 += 32) {
        if (j0 + 32 <= j_end) {
            gl_lds16(Pbase + (size_t)r * T + j0 + 32 + gs * 8, &Ps[p ^ 1][ldsoff]);
            gl_lds16(Vbase + (size_t)r * T + j0 + 32 + gs * 8, &Vs[p ^ 1][ldsoff]);
        }
        short8 a[2], bb[2];
#pragma unroll
        for (int mi = 0; mi < 2; mi++) {
            int row = wi * 32 + mi * 16 + l16;
            a[mi] = *(const short8*)&Ps[p][row * 32 + ((quad ^ ((row >> 1) & 3)) * 8)];
        }
#pragma unroll
        for (int ni = 0; ni < 2; ni++) {
            int row = wn * 32 + ni * 16 + l16;
            bb[ni] = *(const short8*)&Vs[p][row * 32 + ((quad ^ ((row >> 1) & 3)) * 8)];
        }
#pragma unroll
        for (int mi = 0; mi < 2; mi++)
#pragma unroll
            for (int ni = 0; ni < 2; ni++)
                acc[mi][ni] = MFMA16(a[mi], bb[ni], acc[mi][ni]);
        __syncthreads();
        p ^= 1;
    }

#pragma unroll
    for (int mi = 0; mi < 2; mi++)
#pragma unroll
        for (int rr = 0; rr < 4; rr++) {
            int i = ia + wi * 32 + mi * 16 + quad * 4 + rr;
#pragma unroll
            for (int ni = 0; ni < 2; ni++) {
                int d = wn * 32 + ni * 16 + l16;
                y[((size_t)(b * T + i)) * D + h * DH + d] = __float2bfloat16(acc[mi][ni][rr]);
            }
        }
}

// ---------------------------------------------------------------------------
extern "C" void kernel_launch(void* const* d_in, const int* in_sizes, int n_in,
                              void* d_out, int out_size, void* d_ws, size_t ws_size,
                              hipStream_t stream) {
    const int*   idx     = (const int*)d_in[0];
    const float* wte     = (const float*)d_in[1];
    const float* wpe     = (const float*)d_in[2];
    const float* ln1_g   = (const float*)d_in[3];
    const float* ln1_b   = (const float*)d_in[4];
    const float* attn_w  = (const float*)d_in[5];
    const float* attn_b  = (const float*)d_in[6];
    const float* proj_w  = (const float*)d_in[7];
    const float* proj_b  = (const float*)d_in[8];
    const float* dape_gw = (const float*)d_in[9];
    const float* dape_gb = (const float*)d_in[10];
    const float* dape_vw = (const float*)d_in[11];
    const float* dape_vb = (const float*)d_in[12];
    const float* dape_ow = (const float*)d_in[13];
    const float* dape_ob = (const float*)d_in[14];
    const float* ln2_g   = (const float*)d_in[15];
    const float* ln2_b   = (const float*)d_in[16];
    const float* gate_w  = (const float*)d_in[17];
    const float* gate_b  = (const float*)d_in[18];
    const float* val_w   = (const float*)d_in[19];
    const float* val_b   = (const float*)d_in[20];
    const float* mlp_w   = (const float*)d_in[21];
    const float* mlp_b   = (const float*)d_in[22];
    const float* lnf_g   = (const float*)d_in[23];
    const float* lnf_b   = (const float*)d_in[24];
    const float* lm_w    = (const float*)d_in[25];
    float* out = (float*)d_out;

    // Workspace: fp32 region then bf16 region (~175 MB total).
    float* ws   = (float*)d_ws;
    float* x    = ws;                            // B*T*D
    float* att  = x + (size_t)B * T * D;         // B*H*T*T (raw scores)
    bf16*  hb   = (bf16*)(att + (size_t)B * H * T * T);  // B*T*D
    bf16*  yb   = hb   + (size_t)B * T * D;              // B*T*D
    bf16*  ffb  = yb   + (size_t)B * T * D;              // B*T*FF
    bf16*  qkvb = ffb  + (size_t)B * T * FF;             // B*T*3D
    bf16*  vTb  = qkvb + (size_t)B * T * 3 * D;          // B*H*DH*T
    bf16*  Pb   = vTb  + (size_t)B * H * DH * T;         // B*H*T*T (probs)
    bf16*  wq   = Pb   + (size_t)B * H * T * T;          // L*3D*D
    bf16*  wp   = wq   + (size_t)L * 3 * D * D;          // L*D*D
    bf16*  wg   = wp   + (size_t)L * D * D;              // L*FF*D
    bf16*  wv   = wg   + (size_t)L * FF * D;             // L*FF*D
    bf16*  wm   = wv   + (size_t)L * FF * D;             // L*D*FF
    bf16*  wl   = wm   + (size_t)L * D * FF;             // V*D

    auto conv = [&](const float* src, bf16* dst, size_t n) {
        int n4 = (int)(n / 4);
        f2b_k<<<(n4 + 255) / 256, 256, 0, stream>>>(src, dst, n4);
    };
    conv(attn_w, wq, (size_t)L * 3 * D * D);
    conv(proj_w, wp, (size_t)L * D * D);
    conv(gate_w, wg, (size_t)L * FF * D);
    conv(val_w,  wv, (size_t)L * FF * D);
    conv(mlp_w,  wm, (size_t)L * D * FF);
    conv(lm_w,   wl, (size_t)V * D);

    embed_k<<<B * T, 256, 0, stream>>>(idx, wte, wpe, x);

    const int M = B * T;
    for (int l = 0; l < L; l++) {
        ln_bf16_k<<<M, 256, 0, stream>>>(x, ln1_g + l * D, ln1_b + l * D, hb);
        mgemm_k<128, 64, 64, 3><<<dim3(3 * D / 64, M / 128), 256, 0, stream>>>(
            hb, wq + (size_t)l * 3 * D * D, attn_b + l * 3 * D, nullptr, (float*)qkvb, M, 3 * D, D);
        vt_k<<<dim3(T / 64, B * H), 256, 0, stream>>>(qkvb, vTb);
        qk_mfma_k<<<dim3(T / 64, T / 64, B * H), 256, 0, stream>>>(qkvb, att);
        dape_sm_k<<<B * T, 256, 0, stream>>>(att, Pb,
            dape_gw + l * WD * 2 * H, dape_gb + l * WD,
            dape_vw + l * WD * 2 * H, dape_vb + l * WD,
            dape_ow + l * H * WD, dape_ob + l * H);
        av_mfma_k<<<dim3(T / 64, B * H), 256, 0, stream>>>(Pb, vTb, yb);
        mgemm_k<128, 64, 64, 1><<<dim3(D / 64, M / 128), 256, 0, stream>>>(
            yb, wp + (size_t)l * D * D, proj_b + l * D, x, x, M, D, D);
        ln_bf16_k<<<M, 256, 0, stream>>>(x, ln2_g + l * D, ln2_b + l * D, hb);
        mgemm_glu_k<<<dim3(FF / 64, M / 128), 256, 0, stream>>>(
            hb, wg + (size_t)l * FF * D, wv + (size_t)l * FF * D,
            gate_b + l * FF, val_b + l * FF, ffb, M, FF, D);
        mgemm_k<128, 64, 64, 1><<<dim3(D / 64, M / 128), 256, 0, stream>>>(
            ffb, wm + (size_t)l * D * FF, mlp_b + l * D, x, x, M, D, FF);
    }

    ln_bf16_k<<<M, 256, 0, stream>>>(x, lnf_g, lnf_b, hb);
    mgemm_k<128, 64, 64, 2><<<dim3(V / 64, M / 128), 256, 0, stream>>>(
        hb, wl, nullptr, nullptr, out, M, V, D);
}